// Round 5
// baseline (297.662 us; speedup 1.0000x reference)
//
#include <hip/hip_runtime.h>
#include <math.h>

#define MX 512
#define NY 512
#define TWO_PI 6.283185307179586f

// 64 tiles of 64x64 bins.
#define TSHIFT 6
#define TSIDE 8
#define NT 64
#define LDIM 68                   // 64 + 3 halo + 1 spare
#define SLAB (LDIM * LDIM)        // 4624
#define NPB 2048                  // nodes per block (count/place)
#define KPT 8                     // NPB/256 nodes per thread

typedef __attribute__((ext_vector_type(8))) short short8;
typedef __attribute__((ext_vector_type(4))) float float4_t;

__device__ __forceinline__ unsigned short f2bf(float x) {
    union { float f; unsigned u; } v; v.f = x;
    unsigned r = v.u + 0x7fffu + ((v.u >> 16) & 1u);
    return (unsigned short)(r >> 16);
}
__device__ __forceinline__ float bf2f(unsigned short h) {
    union { float f; unsigned u; } v; v.u = ((unsigned)h) << 16;
    return v.f;
}

__device__ __forceinline__ void node_bounds(float2 p, float2 s, float ux, float uy,
                                            float& xl, float& xh, float& yl, float& yh,
                                            float& nw, float& nh) {
    const float SQ2 = 1.41421356237309515f;
    nw = fmaxf(s.x, SQ2 * ux);
    nh = fmaxf(s.y, SQ2 * uy);
    xl = fminf(fmaxf((p.x - 0.5f * nw) / ux, 0.0f), (float)MX);
    xh = fminf(fmaxf((p.x + 0.5f * nw) / ux, 0.0f), (float)MX);
    yl = fminf(fmaxf((p.y - 0.5f * nh) / uy, 0.0f), (float)NY);
    yh = fminf(fmaxf((p.y + 0.5f * nh) / uy, 0.0f), (float)NY);
}

// ---------------------------------------------------------------------------
// K1: count nodes per 64x64 tile (64-entry LDS hist, 977 blocks).
// ---------------------------------------------------------------------------
__global__ __launch_bounds__(256)
void count_kernel(const float2* __restrict__ pos, const float2* __restrict__ size,
                  const float* __restrict__ unit_len,
                  unsigned int* __restrict__ cnt, int n) {
    __shared__ unsigned int h[NT];
    if (threadIdx.x < NT) h[threadIdx.x] = 0;
    __syncthreads();
    float ux = unit_len[0], uy = unit_len[1];
    int start = blockIdx.x * NPB;
    int end = min(start + NPB, n);
#pragma unroll
    for (int k = 0; k < KPT; k++) {
        int i = start + k * 256 + (int)threadIdx.x;
        if (i < end) {
            float xl, xh, yl, yh, nw, nh;
            node_bounds(pos[i], size[i], ux, uy, xl, xh, yl, yh, nw, nh);
            int bx0 = min((int)floorf(xl), MX - 1);
            int by0 = min((int)floorf(yl), NY - 1);
            int t = ((bx0 >> TSHIFT) << 3) | (by0 >> TSHIFT);
            atomicAdd(&h[t], 1u);
        }
    }
    __syncthreads();
    if (threadIdx.x < NT) {
        unsigned int c = h[threadIdx.x];
        if (c) atomicAdd(&cnt[threadIdx.x], c);
    }
}

// ---------------------------------------------------------------------------
// K2: tiny serial exclusive scan over 64 counts.
// ---------------------------------------------------------------------------
__global__ void scan_kernel(const unsigned int* __restrict__ cnt,
                            unsigned int* __restrict__ base,
                            unsigned int* __restrict__ cursor) {
    if (threadIdx.x == 0 && blockIdx.x == 0) {
        unsigned int ex = 0;
        for (int t = 0; t < NT; t++) {
            base[t] = ex;
            cursor[t] = ex;
            ex += cnt[t];
        }
        base[NT] = ex;
    }
}

// ---------------------------------------------------------------------------
// K3: place — compute bounds once (cached in regs), reserve per-tile ranges,
// write (xl,xh,yl,yh | w) payload into tile segments.
// ---------------------------------------------------------------------------
__global__ __launch_bounds__(256)
void place_kernel(const float2* __restrict__ pos, const float2* __restrict__ size,
                  const float* __restrict__ nwt, const float* __restrict__ er,
                  const float* __restrict__ unit_len,
                  const unsigned int* __restrict__ base,
                  unsigned int* __restrict__ cursor,
                  float4* __restrict__ pb, float* __restrict__ pw, int n) {
    __shared__ unsigned int h[NT];
    __shared__ unsigned int bb[NT];
    if (threadIdx.x < NT) h[threadIdx.x] = 0;
    __syncthreads();
    float ux = unit_len[0], uy = unit_len[1];
    int start = blockIdx.x * NPB;
    int end = min(start + NPB, n);

    float cxl[KPT], cxh[KPT], cyl[KPT], cyh[KPT], cw[KPT];
    unsigned int pk[KPT];
#pragma unroll
    for (int k = 0; k < KPT; k++) {
        int i = start + k * 256 + (int)threadIdx.x;
        if (i < end) {
            float2 p = pos[i], s = size[i];
            float xl, xh, yl, yh, nw, nh;
            node_bounds(p, s, ux, uy, xl, xh, yl, yh, nw, nh);
            cxl[k] = xl; cxh[k] = xh; cyl[k] = yl; cyh[k] = yh;
            cw[k] = nwt[i] * er[i] * (s.x * s.y) / (nw * nh);
            int bx0 = min((int)floorf(xl), MX - 1);
            int by0 = min((int)floorf(yl), NY - 1);
            unsigned int t = ((bx0 >> TSHIFT) << 3) | (by0 >> TSHIFT);
            pk[k] = (t << 11) | atomicAdd(&h[t], 1u);
        }
    }
    __syncthreads();
    if (threadIdx.x < NT) {
        unsigned int c = h[threadIdx.x];
        bb[threadIdx.x] = c ? atomicAdd(&cursor[threadIdx.x], c) : 0u;
    }
    __syncthreads();
#pragma unroll
    for (int k = 0; k < KPT; k++) {
        int i = start + k * 256 + (int)threadIdx.x;
        if (i < end) {
            unsigned int t = pk[k] >> 11;
            unsigned int dst = bb[t] + (pk[k] & 2047u);
            if (dst < base[t + 1]) {
                pb[dst] = make_float4(cxl[k], cxh[k], cyl[k], cyh[k]);
                pw[dst] = cw[k];
            }
        }
    }
}

// ---------------------------------------------------------------------------
// K4: accum — spt blocks per tile, each streams its chunk of the tile's
// payload into a private 68x68 LDS tile, plain-stores it to its slab.
// ---------------------------------------------------------------------------
__global__ __launch_bounds__(256)
void accum_kernel(const float4* __restrict__ pb, const float* __restrict__ pw,
                  const unsigned int* __restrict__ base,
                  float* __restrict__ slab, int spt) {
    __shared__ float acc[LDIM][LDIM + 1];
    int t = blockIdx.x / spt;
    int s = blockIdx.x - t * spt;
    int tbx = (t >> 3) << TSHIFT;
    int tby = (t & 7) << TSHIFT;
    for (int e = threadIdx.x; e < SLAB; e += 256)
        acc[e / LDIM][e % LDIM] = 0.0f;
    __syncthreads();

    unsigned int b0 = base[t];
    unsigned int c = base[t + 1] - b0;
    unsigned int chunk = (c + spt - 1) / spt;
    unsigned int ks = s * chunk;
    unsigned int ke = min(c, ks + chunk);
    for (unsigned int k = ks + threadIdx.x; k < ke; k += 256) {
        float4 b4 = pb[b0 + k];
        float w = pw[b0 + k];
        float xl = b4.x, xh = b4.y, yl = b4.z, yh = b4.w;
        int bx0 = min((int)floorf(xl), MX - 1);
        int by0 = min((int)floorf(yl), NY - 1);
        float oxs[4], oys[4];
        int lxs[4], lys[4];
#pragma unroll
        for (int d = 0; d < 4; d++) {
            int ix = bx0 + d;
            float fx = (float)ix;
            oxs[d] = fmaxf(fminf(xh, fx + 1.0f) - fmaxf(xl, fx), 0.0f);
            lxs[d] = min(max(min(ix, MX - 1) - tbx, 0), LDIM - 1);
            int iy = by0 + d;
            float fy = (float)iy;
            oys[d] = fmaxf(fminf(yh, fy + 1.0f) - fmaxf(yl, fy), 0.0f);
            lys[d] = min(max(min(iy, NY - 1) - tby, 0), LDIM - 1);
        }
#pragma unroll
        for (int dx = 0; dx < 4; dx++) {
            if (oxs[dx] == 0.0f) continue;
            float wox = w * oxs[dx];
#pragma unroll
            for (int dy = 0; dy < 4; dy++) {
                float v = wox * oys[dy];
                if (v != 0.0f) atomicAdd(&acc[lxs[dx]][lys[dy]], v);
            }
        }
    }
    __syncthreads();
    float* dst = slab + (size_t)blockIdx.x * SLAB;
    for (int e = threadIdx.x; e < SLAB; e += 256)
        dst[e] = acc[e / LDIM][e % LDIM];
}

// ---------------------------------------------------------------------------
// K5: combine — bin = init + sum of contributing slabs; emit bf16 hi/lo.
// ---------------------------------------------------------------------------
__global__ __launch_bounds__(256)
void combine_kernel(const float* __restrict__ slab,
                    const float* __restrict__ init_dm,
                    unsigned short* __restrict__ dmh,
                    unsigned short* __restrict__ dml, int spt) {
    int idx = blockIdx.x * blockDim.x + threadIdx.x;   // gx*512+gy
    int gx = idx >> 9, gy = idx & 511;
    float sum = init_dm[idx];
    int tx0 = gx >> TSHIFT, ty0 = gy >> TSHIFT;
    int rx = gx & 63, ry = gy & 63;
#pragma unroll
    for (int ax = 0; ax < 2; ax++) {
        int tx = tx0 - ax;
        if (tx < 0 || (ax == 1 && rx > 3)) continue;
        int lx = rx + (ax << TSHIFT);
#pragma unroll
        for (int ay = 0; ay < 2; ay++) {
            int ty = ty0 - ay;
            if (ty < 0 || (ay == 1 && ry > 3)) continue;
            int ly = ry + (ay << TSHIFT);
            const float* s0 = slab + (size_t)(((tx << 3) | ty) * spt) * SLAB
                                   + lx * LDIM + ly;
            for (int s = 0; s < spt; s++) sum += s0[(size_t)s * SLAB];
        }
    }
    unsigned short hi = f2bf(sum);
    dmh[idx] = hi;
    dml[idx] = f2bf(sum - bf2f(hi));
}

// ---------------------------------------------------------------------------
// Tier-C fallback: direct global-atomic scatter into fp32 dm.
// ---------------------------------------------------------------------------
__global__ __launch_bounds__(256)
void scatter_kernel(const float2* __restrict__ pos, const float2* __restrict__ size,
                    const float* __restrict__ nwt, const float* __restrict__ er,
                    const float* __restrict__ unit_len,
                    float* __restrict__ dm, int n) {
    int i = blockIdx.x * blockDim.x + threadIdx.x;
    if (i >= n) return;
    float ux = unit_len[0], uy = unit_len[1];
    float2 p = pos[i], s = size[i];
    float xl, xh, yl, yh, nw, nh;
    node_bounds(p, s, ux, uy, xl, xh, yl, yh, nw, nh);
    float w = nwt[i] * er[i] * (s.x * s.y) / (nw * nh);
    int bx0 = (int)floorf(xl);
    int by0 = (int)floorf(yl);
#pragma unroll
    for (int dx = 0; dx < 4; dx++) {
        int ix = bx0 + dx;
        float fx = (float)ix;
        float ox = fmaxf(fminf(xh, fx + 1.0f) - fmaxf(xl, fx), 0.0f);
        if (ox == 0.0f) continue;
        int rowoff = min(max(ix, 0), MX - 1) * NY;
        float wox = w * ox;
#pragma unroll
        for (int dy = 0; dy < 4; dy++) {
            int iy = by0 + dy;
            float fy = (float)iy;
            float oy = fmaxf(fminf(yh, fy + 1.0f) - fmaxf(yl, fy), 0.0f);
            float v = wox * oy;
            if (v != 0.0f) atomicAdd(&dm[rowoff + min(max(iy, 0), NY - 1)], v);
        }
    }
}

__global__ void cvt_dm_kernel(const float* __restrict__ dm,
                              unsigned short* __restrict__ dmh,
                              unsigned short* __restrict__ dml) {
    int idx = blockIdx.x * blockDim.x + threadIdx.x;
    float x = dm[idx];
    unsigned short hi = f2bf(x);
    dmh[idx] = hi;
    dml[idx] = f2bf(x - bf2f(hi));
}

// ---------------------------------------------------------------------------
// DCT cos matrix, bf16 hi/lo.
// ---------------------------------------------------------------------------
__global__ void gen_cos_kernel(unsigned short* __restrict__ Ch,
                               unsigned short* __restrict__ Cl) {
    int idx = blockIdx.x * blockDim.x + threadIdx.x;
    int a = idx >> 9;
    int j = idx & 511;
    float x = cospif((float)(a * (2 * j + 1)) * (1.0f / 1024.0f));
    unsigned short hi = f2bf(x);
    Ch[idx] = hi;
    Cl[idx] = f2bf(x - bf2f(hi));
}

// ---------------------------------------------------------------------------
// Stage 1 (MFMA): U = dm @ C^T, store U^T bf16 hi/lo.
// ---------------------------------------------------------------------------
__global__ __launch_bounds__(256)
void dct1_mfma_kernel(const unsigned short* __restrict__ dmh,
                      const unsigned short* __restrict__ dml,
                      const unsigned short* __restrict__ Ch,
                      const unsigned short* __restrict__ Cl,
                      unsigned short* __restrict__ UhT,
                      unsigned short* __restrict__ UlT) {
    int lane = threadIdx.x & 63;
    int wv = threadIdx.x >> 6;
    int tile = blockIdx.x * 4 + wv;
    int jt = (tile >> 5) * 16;
    int bt = (tile & 31) * 16;
    int m = lane & 15, q = lane >> 4;
    float4_t acc = {0.f, 0.f, 0.f, 0.f};
    const unsigned short* ah_row = dmh + (jt + m) * 512;
    const unsigned short* al_row = dml + (jt + m) * 512;
    const unsigned short* bh_row = Ch + (bt + m) * 512;
    const unsigned short* bl_row = Cl + (bt + m) * 512;
#pragma unroll 4
    for (int k0 = 0; k0 < 512; k0 += 32) {
        int off = k0 + q * 8;
        short8 ah = *(const short8*)(ah_row + off);
        short8 al = *(const short8*)(al_row + off);
        short8 bh = *(const short8*)(bh_row + off);
        short8 bl = *(const short8*)(bl_row + off);
        acc = __builtin_amdgcn_mfma_f32_16x16x32_bf16(ah, bh, acc, 0, 0, 0);
        acc = __builtin_amdgcn_mfma_f32_16x16x32_bf16(ah, bl, acc, 0, 0, 0);
        acc = __builtin_amdgcn_mfma_f32_16x16x32_bf16(al, bh, acc, 0, 0, 0);
    }
#pragma unroll
    for (int r = 0; r < 4; r++) {
        float v = acc[r];
        unsigned short hi = f2bf(v);
        int addr = (bt + m) * 512 + jt + q * 4 + r;
        UhT[addr] = hi;
        UlT[addr] = f2bf(v - bf2f(hi));
    }
}

// ---------------------------------------------------------------------------
// Stage 2 (MFMA): T = C @ U fused with energy reduce.
// ---------------------------------------------------------------------------
__global__ __launch_bounds__(256)
void dct2_mfma_kernel(const unsigned short* __restrict__ Ch,
                      const unsigned short* __restrict__ Cl,
                      const unsigned short* __restrict__ UhT,
                      const unsigned short* __restrict__ UlT,
                      const float* __restrict__ unit_len,
                      float* __restrict__ out) {
    __shared__ float red[4];
    int lane = threadIdx.x & 63;
    int wv = threadIdx.x >> 6;
    int tile = blockIdx.x * 4 + wv;
    int at = (tile >> 5) * 16;
    int bt = (tile & 31) * 16;
    int m = lane & 15, q = lane >> 4;
    float4_t acc = {0.f, 0.f, 0.f, 0.f};
    const unsigned short* ah_row = Ch + (at + m) * 512;
    const unsigned short* al_row = Cl + (at + m) * 512;
    const unsigned short* bh_row = UhT + (bt + m) * 512;
    const unsigned short* bl_row = UlT + (bt + m) * 512;
#pragma unroll 4
    for (int k0 = 0; k0 < 512; k0 += 32) {
        int off = k0 + q * 8;
        short8 ah = *(const short8*)(ah_row + off);
        short8 al = *(const short8*)(al_row + off);
        short8 bh = *(const short8*)(bh_row + off);
        short8 bl = *(const short8*)(bl_row + off);
        acc = __builtin_amdgcn_mfma_f32_16x16x32_bf16(ah, bh, acc, 0, 0, 0);
        acc = __builtin_amdgcn_mfma_f32_16x16x32_bf16(ah, bl, acc, 0, 0, 0);
        acc = __builtin_amdgcn_mfma_f32_16x16x32_bf16(al, bh, acc, 0, 0, 0);
    }
    float ratio = unit_len[0] / unit_len[1];
    int b = bt + m;
    float wkb = (float)b * (TWO_PI / (float)NY) * ratio;
    float wyb = (b == 0) ? 1.0f : 2.0f;
    float e = 0.0f;
#pragma unroll
    for (int r = 0; r < 4; r++) {
        int a = at + q * 4 + r;
        float wja = (float)a * (TWO_PI / (float)MX);
        float wsq = wja * wja + wkb * wkb;
        float ps = (a == 0 && b == 0) ? 0.0f : (1.0f / wsq);
        float wxa = (a == 0) ? 1.0f : 2.0f;
        e += wxa * wyb * ps * acc[r] * acc[r];
    }
#pragma unroll
    for (int off = 32; off > 0; off >>= 1) e += __shfl_down(e, off, 64);
    if (lane == 0) red[wv] = e;
    __syncthreads();
    if (threadIdx.x == 0) {
        float t = red[0] + red[1] + red[2] + red[3];
        atomicAdd(out, t * (1.0f / ((float)MX * (float)NY)));
    }
}

extern "C" void kernel_launch(void* const* d_in, const int* in_sizes, int n_in,
                              void* d_out, int out_size, void* d_ws, size_t ws_size,
                              hipStream_t stream) {
    const float2* node_pos  = (const float2*)d_in[0];
    const float2* node_size = (const float2*)d_in[1];
    const float*  node_wt   = (const float*)d_in[2];
    const float*  exp_ratio = (const float*)d_in[3];
    const float*  unit_len  = (const float*)d_in[4];
    const float*  init_dm   = (const float*)d_in[5];
    float* out = (float*)d_out;
    int n = in_sizes[2];

    char* wsb = (char*)d_ws;
    size_t off = 0;
    auto alloc = [&](size_t bytes) { void* p = wsb + off; off = (off + bytes + 255) & ~(size_t)255; return p; };
    unsigned short* Ch   = (unsigned short*)alloc((size_t)MX * NY * 2);
    unsigned short* Cl   = (unsigned short*)alloc((size_t)MX * NY * 2);
    unsigned short* dmh  = (unsigned short*)alloc((size_t)MX * NY * 2);
    unsigned short* dml  = (unsigned short*)alloc((size_t)MX * NY * 2);
    unsigned short* UhT  = (unsigned short*)alloc((size_t)MX * NY * 2);
    unsigned short* UlT  = (unsigned short*)alloc((size_t)MX * NY * 2);
    float*          dm     = (float*)alloc((size_t)MX * NY * sizeof(float));  // tier C only
    unsigned int*   cnt    = (unsigned int*)alloc(NT * sizeof(unsigned int));
    unsigned int*   tbase  = (unsigned int*)alloc((NT + 1) * sizeof(unsigned int));
    unsigned int*   cursor = (unsigned int*)alloc(NT * sizeof(unsigned int));
    float4*         pb     = (float4*)alloc((size_t)n * sizeof(float4));
    float*          pw     = (float*)alloc((size_t)n * sizeof(float));
    bool binned = (off <= ws_size);
    int spt = 0;
    float* slab = nullptr;
    if (binned) {
        size_t avail = ws_size - off;
        size_t per_spt = (size_t)NT * SLAB * sizeof(float);
        spt = (int)(avail / per_spt);
        if (spt > 32) spt = 32;
        if (spt < 1) binned = false;
        else slab = (float*)alloc((size_t)NT * spt * SLAB * sizeof(float));
    }

    hipMemsetAsync(d_out, 0, sizeof(float), stream);
    gen_cos_kernel<<<(MX * NY) / 256, 256, 0, stream>>>(Ch, Cl);

    if (binned) {
        hipMemsetAsync(cnt, 0, NT * sizeof(unsigned int), stream);
        int nblk = (n + NPB - 1) / NPB;
        count_kernel<<<nblk, 256, 0, stream>>>(node_pos, node_size, unit_len, cnt, n);
        scan_kernel<<<1, 64, 0, stream>>>(cnt, tbase, cursor);
        place_kernel<<<nblk, 256, 0, stream>>>(
            node_pos, node_size, node_wt, exp_ratio, unit_len, tbase, cursor,
            pb, pw, n);
        accum_kernel<<<NT * spt, 256, 0, stream>>>(pb, pw, tbase, slab, spt);
        combine_kernel<<<(MX * NY) / 256, 256, 0, stream>>>(slab, init_dm, dmh, dml, spt);
    } else {
        hipMemcpyAsync(dm, init_dm, (size_t)MX * NY * sizeof(float),
                       hipMemcpyDeviceToDevice, stream);
        scatter_kernel<<<(n + 255) / 256, 256, 0, stream>>>(
            node_pos, node_size, node_wt, exp_ratio, unit_len, dm, n);
        cvt_dm_kernel<<<(MX * NY) / 256, 256, 0, stream>>>(dm, dmh, dml);
    }

    dct1_mfma_kernel<<<256, 256, 0, stream>>>(dmh, dml, Ch, Cl, UhT, UlT);
    dct2_mfma_kernel<<<256, 256, 0, stream>>>(Ch, Cl, UhT, UlT, unit_len, out);
}